// Round 19
// baseline (174.466 us; speedup 1.0000x reference)
//
#include <hip/hip_runtime.h>
#include <stdint.h>

#define EPS_NORM 1e-12f
#define F32_TINY 1.17549435e-38f

static __device__ __forceinline__ int rfl(int v) {
  return __builtin_amdgcn_readfirstlane(v);
}

// ---------------- Threefry2x32 (exact JAX replica, 20 rounds) ----------------
__device__ __forceinline__ void threefry2x32(uint32_t k0, uint32_t k1,
                                             uint32_t x0, uint32_t x1,
                                             uint32_t& o0, uint32_t& o1) {
  uint32_t ks2 = k0 ^ k1 ^ 0x1BD11BDAu;
  x0 += k0; x1 += k1;
#define TF_ROT(r) { x0 += x1; x1 = (x1 << (r)) | (x1 >> (32 - (r))); x1 ^= x0; }
  TF_ROT(13) TF_ROT(15) TF_ROT(26) TF_ROT(6)
  x0 += k1; x1 += ks2 + 1u;
  TF_ROT(17) TF_ROT(29) TF_ROT(16) TF_ROT(24)
  x0 += ks2; x1 += k0 + 2u;
  TF_ROT(13) TF_ROT(15) TF_ROT(26) TF_ROT(6)
  x0 += k0; x1 += k1 + 3u;
  TF_ROT(17) TF_ROT(29) TF_ROT(16) TF_ROT(24)
  x0 += k1; x1 += ks2 + 4u;
  TF_ROT(13) TF_ROT(15) TF_ROT(26) TF_ROT(6)
  x0 += ks2; x1 += k0 + 5u;
#undef TF_ROT
  o0 = x0; o1 = x1;
}

// P(p) = (p&7)*8 + (p>>3): involution used for T1's coalesced permuted layout.
#define PERM_IDX(p) ((((p) & 7) << 3) | ((p) >> 3))

// ========== PHASE 1 mega-kernel: T1 + T2c + ui + init ========================
// (verbatim R16/R18: conflicts 0; init role zeroes wkg2 for k_step4)
__global__ __launch_bounds__(256) void k_phase1(
    const float* __restrict__ E, const int* __restrict__ allc,
    const float* __restrict__ W1, const float* __restrict__ b1,
    const float* __restrict__ W2, const float* __restrict__ b2,
    const float* __restrict__ U, const int* __restrict__ users,
    const float* __restrict__ Iemb, const float* __restrict__ uiW,
    const float* __restrict__ uib, const int* __restrict__ kg,
    float* __restrict__ T1, float* __restrict__ T2c,
    float* __restrict__ uiE, float* __restrict__ out0, float* __restrict__ out2,
    int* __restrict__ wkg2) {
  __shared__ float SM[8192];
  const int blk = blockIdx.x, tid = threadIdx.x;
  const int wv = tid >> 6, lane = tid & 63;
  const int NT1B = 782, NT2B = 25, NUIB = 256;
  if (blk < NT1B + NT2B) {
    const bool isT1 = blk < NT1B;
    {
      const float* W = isT1 ? W1 : W2;
      for (int idx = tid; idx < 4096; idx += 256) {
        int k = idx >> 6, c = idx & 63;
        int cg = c & 7, ci = c >> 3;
        SM[k * 64 + ((ci >> 2) * 8 + cg) * 4 + (ci & 3)] = W[idx];
      }
    }
    __syncthreads();
    const int rg = lane >> 3, cg = lane & 7;
    const int sub = lane >> 5, r = lane & 31;
    const float* bias = isT1 ? b1 : b2;
    float bv[8];
#pragma unroll
    for (int ci = 0; ci < 8; ++ci) bv[ci] = bias[ci * 8 + cg];
    float* eTw = SM + 4096 + wv * 1024;
    const float4* eT4 = reinterpret_cast<const float4*>(eTw);
    const float4* W4 = reinterpret_cast<const float4*>(SM);
#pragma unroll 1
    for (int t = 0; t < 2; ++t) {
      int batch = (isT1 ? blk : blk - NT1B) * 2 + t;
      int rbase = batch * 128 + wv * 32;
      if (isT1 && rbase >= 200000) continue;
      int srow = isT1 ? (rbase + r) : allc[rbase + r];
      const float4* Er = reinterpret_cast<const float4*>(E + (size_t)srow * 64);
      float4 a0 = Er[sub * 4 + 0], a1 = Er[sub * 4 + 1];
      float4 a2 = Er[sub * 4 + 2], a3 = Er[sub * 4 + 3];
      float4 a4 = Er[8 + sub * 4 + 0], a5 = Er[8 + sub * 4 + 1];
      float4 a6 = Er[8 + sub * 4 + 2], a7 = Er[8 + sub * 4 + 3];
      float y[4][8];
#pragma unroll
      for (int ri = 0; ri < 4; ++ri)
#pragma unroll
        for (int ci = 0; ci < 8; ++ci) y[ri][ci] = 0.f;
      {
        float ev[16] = {a0.x, a0.y, a0.z, a0.w, a1.x, a1.y, a1.z, a1.w,
                        a2.x, a2.y, a2.z, a2.w, a3.x, a3.y, a3.z, a3.w};
#pragma unroll
        for (int kk = 0; kk < 16; ++kk)
          eTw[(sub * 16 + kk) * 32 + r] = ev[kk];
#pragma unroll 8
        for (int kk = 0; kk < 32; ++kk) {
          float4 e4 = eT4[kk * 8 + rg];
          float4 wa = W4[kk * 16 + cg];
          float4 wb = W4[kk * 16 + 8 + cg];
          float ev4[4] = {e4.x, e4.y, e4.z, e4.w};
          float wv8[8] = {wa.x, wa.y, wa.z, wa.w, wb.x, wb.y, wb.z, wb.w};
#pragma unroll
          for (int ri = 0; ri < 4; ++ri)
#pragma unroll
            for (int ci = 0; ci < 8; ++ci)
              y[ri][ci] = fmaf(ev4[ri], wv8[ci], y[ri][ci]);
        }
      }
      {
        float ev[16] = {a4.x, a4.y, a4.z, a4.w, a5.x, a5.y, a5.z, a5.w,
                        a6.x, a6.y, a6.z, a6.w, a7.x, a7.y, a7.z, a7.w};
#pragma unroll
        for (int kk = 0; kk < 16; ++kk)
          eTw[(sub * 16 + kk) * 32 + r] = ev[kk];
#pragma unroll 8
        for (int kk = 0; kk < 32; ++kk) {
          float4 e4 = eT4[kk * 8 + rg];
          float4 wa = W4[(32 + kk) * 16 + cg];
          float4 wb = W4[(32 + kk) * 16 + 8 + cg];
          float ev4[4] = {e4.x, e4.y, e4.z, e4.w};
          float wv8[8] = {wa.x, wa.y, wa.z, wa.w, wb.x, wb.y, wb.z, wb.w};
#pragma unroll
          for (int ri = 0; ri < 4; ++ri)
#pragma unroll
            for (int ci = 0; ci < 8; ++ci)
              y[ri][ci] = fmaf(ev4[ri], wv8[ci], y[ri][ci]);
        }
      }
#pragma unroll
      for (int ri = 0; ri < 4; ++ri)
#pragma unroll
        for (int ci = 0; ci < 8; ++ci)
          y[ri][ci] = __fadd_rn(y[ri][ci], bv[ci]);
#pragma unroll
      for (int ri = 0; ri < 4; ++ri) {
        float A0 = __fadd_rn(__fmul_rn(y[ri][0], y[ri][0]),
                             __fmul_rn(y[ri][4], y[ri][4]));
        float A1 = __fadd_rn(__fmul_rn(y[ri][1], y[ri][1]),
                             __fmul_rn(y[ri][5], y[ri][5]));
        float A2 = __fadd_rn(__fmul_rn(y[ri][2], y[ri][2]),
                             __fmul_rn(y[ri][6], y[ri][6]));
        float A3 = __fadd_rn(__fmul_rn(y[ri][3], y[ri][3]),
                             __fmul_rn(y[ri][7], y[ri][7]));
        float B0 = __fadd_rn(A0, A2), B1 = __fadd_rn(A1, A3);
        float C = __fadd_rn(B0, B1);
        C = __fadd_rn(C, __shfl_xor(C, 4));
        C = __fadd_rn(C, __shfl_xor(C, 2));
        C = __fadd_rn(C, __shfl_xor(C, 1));
        float denom = fmaxf(sqrtf(C), EPS_NORM);
        int row = rbase + rg * 4 + ri;
        if (isT1) {
          float4* drow = reinterpret_cast<float4*>(T1 + (size_t)row * 64 + cg * 8);
          drow[0] = make_float4(y[ri][0] / denom, y[ri][1] / denom,
                                y[ri][2] / denom, y[ri][3] / denom);
          drow[1] = make_float4(y[ri][4] / denom, y[ri][5] / denom,
                                y[ri][6] / denom, y[ri][7] / denom);
        } else {
          float* drow = T2c + (size_t)row * 64;
#pragma unroll
          for (int ci = 0; ci < 8; ++ci) drow[ci * 8 + cg] = y[ri][ci] / denom;
        }
      }
    }
  } else if (blk < NT1B + NT2B + NUIB) {
    int ub = blk - (NT1B + NT2B);
    for (int i = tid; i < 8192; i += 256) SM[i] = uiW[i];
    __syncthreads();
    float bl = uib[lane];
#pragma unroll 1
    for (int t = 0; t < 4; ++t) {
      int b = ub * 16 + wv * 4 + t;
      int usr = rfl(users[b]);
      const float* ur = U + (size_t)usr * 64;
      const float* ir = Iemb + (size_t)b * 64;
      float y = 0.f;
#pragma unroll
      for (int k = 0; k < 64; ++k) y = fmaf(ur[k], SM[k * 64 + lane], y);
#pragma unroll
      for (int k = 0; k < 64; ++k) y = fmaf(ir[k], SM[(64 + k) * 64 + lane], y);
      y += bl;
      float ss = y * y;
#pragma unroll
      for (int off = 32; off; off >>= 1) ss += __shfl_xor(ss, off);
      float yn = y / fmaxf(sqrtf(ss), EPS_NORM);
      uiE[(size_t)b * 64 + lane] = yn;
    }
  } else {
    const int4* kg4 = reinterpret_cast<const int4*>(kg);
    float4* o4 = reinterpret_cast<float4*>(out0);
    float4* o24 = reinterpret_cast<float4*>(out2);
    int4* wz = reinterpret_cast<int4*>(wkg2);
    int4 z; z.x = 0; z.y = 0; z.z = 0; z.w = 0;
    for (int i = (blk - 1063) * 256 + tid; i < 800000; i += 200 * 256) {
      int4 v = kg4[i];
      float4 f = make_float4((float)v.x, (float)v.y, (float)v.z, (float)v.w);
      o4[i] = f;
      o24[i] = f;
      wz[i] = z;
    }
  }
}

// ====== FUSED STEP4 (path A): cooperative phase A + DUAL-SLOT B/C ===========
__global__ __launch_bounds__(256) void k_step4(
    const int* __restrict__ items, const int* __restrict__ users,
    const int* __restrict__ kg, const int* __restrict__ nrel,
    const int* __restrict__ allc, const float* __restrict__ E,
    const float* __restrict__ T1, const float* __restrict__ T2c,
    const float* __restrict__ uiE, const float* __restrict__ U,
    float* __restrict__ out0, float* __restrict__ ap1_out,
    int* __restrict__ s1i_g, float* __restrict__ lmp1,
    float* __restrict__ p2, int* __restrict__ wkg2) {
  __shared__ int s1_idx_sh[4][4], s1_rel_sh[4][4], s1_ent_sh[4][4];
  __shared__ int kept_sh[4][2][32];
  __shared__ float scoreA[4][64];
  const int tid = threadIdx.x, wv = tid >> 6, lane = tid & 63;
  const int blk = blockIdx.x;
  // ---------------- phase A: cooperative score1 (verbatim R18) --------------
  {
    const int b = blk * 4 + wv;
    const int item = rfl(items[b]);
    int nbAll = kg[(size_t)item * 64 + lane];
    const int g = lane >> 2, q = lane & 3;
    float uu[4][4];
#pragma unroll
    for (int f = 0; f < 4; ++f)
#pragma unroll
      for (int e = 0; e < 4; ++e) {
        int j = ((q & 1) << 5) + 8 * e + 2 * f + ((q >> 1) & 1);
        uu[f][e] = uiE[(size_t)b * 64 + j];
      }
#pragma unroll 1
    for (int pass = 0; pass < 4; ++pass) {
      int rowIdx = pass * 16 + g;
      int nbr = __shfl(nbAll, rowIdx);
      const float4* R = reinterpret_cast<const float4*>(T1 + (size_t)nbr * 64);
      float4 v0 = R[q], v1 = R[4 + q], v2 = R[8 + q], v3 = R[12 + q];
      float vv[4][4] = {{v0.x, v0.y, v0.z, v0.w}, {v1.x, v1.y, v1.z, v1.w},
                        {v2.x, v2.y, v2.z, v2.w}, {v3.x, v3.y, v3.z, v3.w}};
      float pr[4][4];
#pragma unroll
      for (int f = 0; f < 4; ++f)
#pragma unroll
        for (int e = 0; e < 4; ++e)
          pr[e][f] = __fmul_rn(vv[f][e], uu[f][e]);
      float dd[4][4];
#pragma unroll
      for (int e = 0; e < 4; ++e)
#pragma unroll
        for (int f = 0; f < 4; ++f)
          dd[e][f] = __fadd_rn(pr[e][f], __shfl_xor(pr[e][f], 1));
#pragma unroll
      for (int f = 0; f < 4; ++f) {
        dd[0][f] = __fadd_rn(dd[0][f], dd[2][f]);
        dd[1][f] = __fadd_rn(dd[1][f], dd[3][f]);
      }
#pragma unroll
      for (int f = 0; f < 4; ++f)
        dd[0][f] = __fadd_rn(dd[0][f], dd[1][f]);
      float t0 = __fadd_rn(dd[0][0], dd[0][2]);
      float t1 = __fadd_rn(dd[0][1], dd[0][3]);
      float uh = __fadd_rn(t0, t1);
      float sF = __fadd_rn(uh, __shfl_xor(uh, 2));
      if (q == 0) scoreA[wv][rowIdx] = sF;
    }
    float s = scoreA[wv][lane];
    int nb = nbAll;
    float m = s;
#pragma unroll
    for (int off = 32; off; off >>= 1) m = fmaxf(m, __shfl_xor(m, off));
    float ex = expf(s - m);
    float sum = ex;
#pragma unroll
    for (int off = 32; off; off >>= 1) sum += __shfl_xor(sum, off);
    float p = ex / sum;
    int rank = 0;
    for (int k2 = 0; k2 < 64; ++k2) {
      float pv = __shfl(p, k2);
      rank += (pv > p || (pv == p && k2 < lane)) ? 1 : 0;
    }
    float acc = 0.f;
#pragma unroll
    for (int rr = 0; rr < 4; ++rr) {
      unsigned long long msk = __ballot(rank == rr);
      int src = __ffsll(msk) - 1;
      acc += __shfl(p, src);
    }
    float lm = logf(acc * 0.25f);
    if (lane == 0) { ap1_out[b] = lm; lmp1[b] = lm; }
    if (rank < 4) {
      s1_idx_sh[wv][rank] = lane;
      s1_ent_sh[wv][rank] = nb;
      s1_rel_sh[wv][rank] = nrel[(size_t)item * 64 + lane];
      s1i_g[b * 4 + rank] = lane;
      out0[(size_t)item * 64 + lane] = 0.0f;
    }
  }
  __syncthreads();
  // ------- phases B + C: dual-slot batching (2 independent chains) ----------
#pragma unroll 1
  for (int sp = 0; sp < 4; sp += 2) {
    const int b0 = blk * 4 + sp, b1 = b0 + 1;
    const int item0 = rfl(items[b0]), item1 = rfl(items[b1]);
    const int n0 = b0 * 4 + wv, n1 = b1 * 4 + wv;
    const int rel0 = rfl(s1_rel_sh[sp][wv]), rel1 = rfl(s1_rel_sh[sp + 1][wv]);
    const int repl0 = rfl(s1_ent_sh[sp][wv]), repl1 = rfl(s1_ent_sh[sp + 1][wv]);
    const int colsel0 = rfl(s1_idx_sh[sp][wv]), colsel1 = rfl(s1_idx_sh[sp + 1][wv]);
    // ---- phase B x2 (each chain verbatim serial-ascending) ----
    {
      int usr0 = rfl(users[b0]), usr1 = rfl(users[b1]);
      int ent0 = allc[rel0 * 64 + lane], ent1 = allc[rel1 * 64 + lane];
      const float* ur0 = U + (size_t)usr0 * 64;
      const float* ur1 = U + (size_t)usr1 * 64;
      const float4* e40 = reinterpret_cast<const float4*>(E + (size_t)ent0 * 64);
      const float4* e41 = reinterpret_cast<const float4*>(E + (size_t)ent1 * 64);
      float s0 = 0.f, s1v = 0.f;
#pragma unroll
      for (int j4 = 0; j4 < 16; ++j4) {
        float4 t0 = e40[j4];
        float4 t1 = e41[j4];
        s0 = fmaf(ur0[4 * j4 + 0], t0.x, s0);
        s0 = fmaf(ur0[4 * j4 + 1], t0.y, s0);
        s0 = fmaf(ur0[4 * j4 + 2], t0.z, s0);
        s0 = fmaf(ur0[4 * j4 + 3], t0.w, s0);
        s1v = fmaf(ur1[4 * j4 + 0], t1.x, s1v);
        s1v = fmaf(ur1[4 * j4 + 1], t1.y, s1v);
        s1v = fmaf(ur1[4 * j4 + 2], t1.z, s1v);
        s1v = fmaf(ur1[4 * j4 + 3], t1.w, s1v);
      }
      int rank0 = 0, rank1 = 0;
      for (int k2 = 0; k2 < 64; ++k2) {
        float sv0 = __shfl(s0, k2);
        float sv1 = __shfl(s1v, k2);
        rank0 += (sv0 > s0 || (sv0 == s0 && k2 < lane)) ? 1 : 0;
        rank1 += (sv1 > s1v || (sv1 == s1v && k2 < lane)) ? 1 : 0;
      }
      if (rank0 < 32) kept_sh[wv][0][rank0] = (lane << 18) | ent0;
      if (rank1 < 32) kept_sh[wv][1][rank1] = (lane << 18) | ent1;
    }
    // ---- phase C x2 (each chain verbatim) ----
    {
      int m = lane & 31;
      int pk0 = kept_sh[wv][0][m];        // same-wave LDS dep
      int pk1 = kept_sh[wv][1][m];
      int c0 = pk0 >> 18, c1 = pk1 >> 18;
      int ent0 = pk0 & 0x3FFFF, ent1 = pk1 & 0x3FFFF;
      float q0 = uiE[(size_t)b0 * 64 + PERM_IDX(lane)] *
                 T1[(size_t)repl0 * 64 + lane];
      float q1 = uiE[(size_t)b1 * 64 + PERM_IDX(lane)] *
                 T1[(size_t)repl1 * 64 + lane];
      const float4* c40 = reinterpret_cast<const float4*>(
          T2c + ((size_t)rel0 * 64 + c0) * 64);
      const float4* c41 = reinterpret_cast<const float4*>(
          T2c + ((size_t)rel1 * 64 + c1) * 64);
      float s0 = 0.f, s1v = 0.f;
#pragma unroll
      for (int j4 = 0; j4 < 16; ++j4) {
        float4 t0 = c40[j4];
        float4 t1 = c41[j4];
        s0 = fmaf(__shfl(q0, PERM_IDX(4 * j4 + 0)), t0.x, s0);
        s0 = fmaf(__shfl(q0, PERM_IDX(4 * j4 + 1)), t0.y, s0);
        s0 = fmaf(__shfl(q0, PERM_IDX(4 * j4 + 2)), t0.z, s0);
        s0 = fmaf(__shfl(q0, PERM_IDX(4 * j4 + 3)), t0.w, s0);
        s1v = fmaf(__shfl(q1, PERM_IDX(4 * j4 + 0)), t1.x, s1v);
        s1v = fmaf(__shfl(q1, PERM_IDX(4 * j4 + 1)), t1.y, s1v);
        s1v = fmaf(__shfl(q1, PERM_IDX(4 * j4 + 2)), t1.z, s1v);
        s1v = fmaf(__shfl(q1, PERM_IDX(4 * j4 + 3)), t1.w, s1v);
      }
      float mx0 = s0, mx1 = s1v;
#pragma unroll
      for (int off = 1; off < 32; off <<= 1) {
        mx0 = fmaxf(mx0, __shfl_xor(mx0, off));
        mx1 = fmaxf(mx1, __shfl_xor(mx1, off));
      }
      float shv0 = s0 - mx0, shv1 = s1v - mx1;
      float se0 = expf(shv0), se1 = expf(shv1);
      float sum0 = se0, sum1 = se1;
#pragma unroll
      for (int off = 1; off < 32; off <<= 1) {
        sum0 += __shfl_xor(sum0, off);
        sum1 += __shfl_xor(sum1, off);
      }
      float logp0 = shv0 - logf(sum0);
      float logp1 = shv1 - logf(sum1);
      uint32_t h0a, h1a, h0b, h1b;
      threefry2x32(0u, 42u, 0u, (uint32_t)(n0 * 32 + m), h0a, h1a);
      threefry2x32(0u, 42u, 0u, (uint32_t)(n1 * 32 + m), h0b, h1b);
      uint32_t bits0 = h0a ^ h1a, bits1 = h0b ^ h1b;
      float u00 = __uint_as_float((bits0 >> 9) | 0x3F800000u) - 1.0f;
      float u01 = __uint_as_float((bits1 >> 9) | 0x3F800000u) - 1.0f;
      float g0 = -logf(-logf(fmaxf(u00, F32_TINY)));
      float g1 = -logf(-logf(fmaxf(u01, F32_TINY)));
      float z0 = g0 + logp0, z1 = g1 + logp1;
      float bz0 = z0, bz1 = z1;
      int bm0 = m, bm1 = m;
#pragma unroll
      for (int off = 1; off < 32; off <<= 1) {
        float oz0 = __shfl_xor(bz0, off);
        int om0 = __shfl_xor(bm0, off);
        if (oz0 > bz0 || (oz0 == bz0 && om0 < bm0)) { bz0 = oz0; bm0 = om0; }
        float oz1 = __shfl_xor(bz1, off);
        int om1 = __shfl_xor(bm1, off);
        if (oz1 > bz1 || (oz1 == bz1 && om1 < bm1)) { bz1 = oz1; bm1 = om1; }
      }
      if (lane == bm0) {
        p2[n0] = expf(logp0);
        atomicMax(&wkg2[(size_t)item0 * 64 + colsel0], ((b0 + 1) << 18) | ent0);
      }
      if (lane == bm1) {
        p2[n1] = expf(logp1);
        atomicMax(&wkg2[(size_t)item1 * 64 + colsel1], ((b1 + 1) << 18) | ent1);
      }
    }
  }
}

// --------- finalize (path A): patch 16K cells of out2 + ap2 ------------------
__global__ __launch_bounds__(256) void k_fin2(
    const int* __restrict__ items, const int* __restrict__ s1_idx,
    const int* __restrict__ wkg2, const float* __restrict__ p2,
    const float* __restrict__ lmp1,
    float* __restrict__ out2, float* __restrict__ out3, int N, int B) {
  int i = blockIdx.x * 256 + threadIdx.x;
  if (i < N) {
    int b = i >> 2;
    int item = items[b];
    int col = s1_idx[i];
    int v = wkg2[(size_t)item * 64 + col];
    out2[(size_t)item * 64 + col] = (float)(v & 0x3FFFF);
  }
  if (i < B) {
    float a = ((p2[i * 4] + p2[i * 4 + 1]) + p2[i * 4 + 2]) + p2[i * 4 + 3];
    out3[i] = lmp1[i] + logf(a * 0.25f);
  }
}

// ================= fallback-path kernels (path B, unchanged) =================
__global__ __launch_bounds__(256) void k_init(const int* __restrict__ kg,
                                              float* __restrict__ out0,
                                              int* __restrict__ wkg2, int n) {
  int i = blockIdx.x * 256 + threadIdx.x;
  if (i < n) { int v = kg[i]; out0[i] = (float)v; wkg2[i] = v; }
}

__device__ __forceinline__ void transform_row(const float4* __restrict__ Er,
                                              const float* __restrict__ W,
                                              const float* __restrict__ bias,
                                              float (&yn)[64]) {
  float y[64];
#pragma unroll
  for (int j = 0; j < 64; ++j) y[j] = 0.f;
  float4 c0 = Er[0], c1 = Er[1], c2 = Er[2], c3 = Er[3];
#pragma unroll 1
  for (int cc = 0; cc < 4; ++cc) {
    float4 n0, n1, n2, n3;
    if (cc < 3) { n0 = Er[cc * 4 + 4]; n1 = Er[cc * 4 + 5];
                  n2 = Er[cc * 4 + 6]; n3 = Er[cc * 4 + 7]; }
    float ev[16] = {c0.x, c0.y, c0.z, c0.w, c1.x, c1.y, c1.z, c1.w,
                    c2.x, c2.y, c2.z, c2.w, c3.x, c3.y, c3.z, c3.w};
#pragma unroll
    for (int k2i = 0; k2i < 16; ++k2i) {
      const float4* Wr = reinterpret_cast<const float4*>(
          W + ((size_t)(cc * 16 + k2i)) * 64);
      float ek = ev[k2i];
#pragma unroll
      for (int j4 = 0; j4 < 16; ++j4) {
        float4 w = Wr[j4];
        y[j4 * 4 + 0] = fmaf(ek, w.x, y[j4 * 4 + 0]);
        y[j4 * 4 + 1] = fmaf(ek, w.y, y[j4 * 4 + 1]);
        y[j4 * 4 + 2] = fmaf(ek, w.z, y[j4 * 4 + 2]);
        y[j4 * 4 + 3] = fmaf(ek, w.w, y[j4 * 4 + 3]);
      }
    }
    c0 = n0; c1 = n1; c2 = n2; c3 = n3;
  }
  const float4* B4 = reinterpret_cast<const float4*>(bias);
#pragma unroll
  for (int j4 = 0; j4 < 16; ++j4) {
    float4 bb = B4[j4];
    float bv[4] = {bb.x, bb.y, bb.z, bb.w};
#pragma unroll
    for (int t = 0; t < 4; ++t) y[j4 * 4 + t] = __fadd_rn(y[j4 * 4 + t], bv[t]);
  }
  float S1[32];
#pragma unroll
  for (int i = 0; i < 32; ++i)
    S1[i] = __fadd_rn(__fmul_rn(y[i], y[i]), __fmul_rn(y[i + 32], y[i + 32]));
#pragma unroll
  for (int i = 0; i < 16; ++i) S1[i] = __fadd_rn(S1[i], S1[i + 16]);
#pragma unroll
  for (int i = 0; i < 8; ++i)  S1[i] = __fadd_rn(S1[i], S1[i + 8]);
#pragma unroll
  for (int i = 0; i < 4; ++i)  S1[i] = __fadd_rn(S1[i], S1[i + 4]);
#pragma unroll
  for (int i = 0; i < 2; ++i)  S1[i] = __fadd_rn(S1[i], S1[i + 2]);
  float ss = __fadd_rn(S1[0], S1[1]);
  float denom = fmaxf(sqrtf(ss), EPS_NORM);
#pragma unroll
  for (int j = 0; j < 64; ++j) yn[j] = y[j] / denom;
}

__global__ __launch_bounds__(256) void k_transform64(
    const float* __restrict__ src, const int* __restrict__ gidx,
    const float* __restrict__ W, const float* __restrict__ bias,
    float* __restrict__ out, int nrows) {
  __shared__ float Wl[4096];
  for (int i = threadIdx.x; i < 4096; i += 256) Wl[i] = W[i];
  __syncthreads();
  int wid = threadIdx.x >> 6, lane = threadIdx.x & 63;
  int row = rfl(blockIdx.x * 4 + wid);
  if (row >= nrows) return;
  int srow = rfl(gidx ? gidx[row] : row);
  const float* er = src + (size_t)srow * 64;
  float y = 0.f;
#pragma unroll
  for (int k = 0; k < 64; ++k) y = fmaf(er[k], Wl[k * 64 + lane], y);
  y += bias[lane];
  float ss = y * y;
#pragma unroll
  for (int off = 32; off; off >>= 1) ss += __shfl_xor(ss, off);
  float yn = y / fmaxf(sqrtf(ss), EPS_NORM);
  out[(size_t)row * 64 + lane] = yn;
}

__global__ __launch_bounds__(256) void k_ui(
    const float* __restrict__ U, const int* __restrict__ users,
    const float* __restrict__ Iemb, const float* __restrict__ W,
    const float* __restrict__ bias, float* __restrict__ out, int B) {
  __shared__ float Wl[8192];
  for (int i = threadIdx.x; i < 8192; i += 256) Wl[i] = W[i];
  __syncthreads();
  int wid = threadIdx.x >> 6, lane = threadIdx.x & 63;
  int b = rfl(blockIdx.x * 4 + wid);
  if (b >= B) return;
  int usr = rfl(users[b]);
  const float* ur = U + (size_t)usr * 64;
  const float* ir = Iemb + (size_t)b * 64;
  float y = 0.f;
#pragma unroll
  for (int k = 0; k < 64; ++k) y = fmaf(ur[k], Wl[k * 64 + lane], y);
#pragma unroll
  for (int k = 0; k < 64; ++k) y = fmaf(ir[k], Wl[(64 + k) * 64 + lane], y);
  y += bias[lane];
  float ss = y * y;
#pragma unroll
  for (int off = 32; off; off >>= 1) ss += __shfl_xor(ss, off);
  float yn = y / fmaxf(sqrtf(ss), EPS_NORM);
  out[(size_t)b * 64 + lane] = yn;
}

__device__ __forceinline__ void score1_tail(
    float s, int lane, int b, int item, int nb,
    const int* __restrict__ nrel,
    float* __restrict__ out0, float* __restrict__ ap1_out,
    int* __restrict__ s1_idx, int* __restrict__ s1_rel, int* __restrict__ s1_ent,
    float* __restrict__ lmp1, int* __restrict__ wkg2) {
  float m = s;
#pragma unroll
  for (int off = 32; off; off >>= 1) m = fmaxf(m, __shfl_xor(m, off));
  float ex = expf(s - m);
  float sum = ex;
#pragma unroll
  for (int off = 32; off; off >>= 1) sum += __shfl_xor(sum, off);
  float p = ex / sum;
  int rank = 0;
  for (int k2 = 0; k2 < 64; ++k2) {
    float pv = __shfl(p, k2);
    rank += (pv > p || (pv == p && k2 < lane)) ? 1 : 0;
  }
  float acc = 0.f;
#pragma unroll
  for (int rr = 0; rr < 4; ++rr) {
    unsigned long long msk = __ballot(rank == rr);
    int src = __ffsll(msk) - 1;
    acc += __shfl(p, src);
  }
  float lm = logf(acc * 0.25f);
  if (lane == 0) { ap1_out[b] = lm; lmp1[b] = lm; }
  if (rank < 4) {
    s1_idx[b * 4 + rank] = lane;
    s1_ent[b * 4 + rank] = nb;
    s1_rel[b * 4 + rank] = nrel[(size_t)item * 64 + lane];
    out0[(size_t)item * 64 + lane] = 0.0f;
    wkg2[(size_t)item * 64 + lane] = 0;
  }
}

__global__ __launch_bounds__(256) void k_score1(
    const int* __restrict__ items, const int* __restrict__ kg,
    const int* __restrict__ nrel, const float* __restrict__ E,
    const float* __restrict__ W1, const float* __restrict__ b1,
    const float* __restrict__ uiE,
    float* __restrict__ out0, float* __restrict__ ap1_out,
    int* __restrict__ s1_idx, int* __restrict__ s1_rel, int* __restrict__ s1_ent,
    float* __restrict__ lmp1, int* __restrict__ wkg2) {
  int tid = threadIdx.x, wv = tid >> 6, lane = tid & 63;
  int b = rfl(blockIdx.x * 4 + wv);
  int item = rfl(items[b]);
  int nb = kg[(size_t)item * 64 + lane];
  const float4* Er = reinterpret_cast<const float4*>(E + (size_t)nb * 64);
  float yn[64];
  transform_row(Er, W1, b1, yn);
  const float4* Ur = reinterpret_cast<const float4*>(uiE + (size_t)b * 64);
  float D[32];
#pragma unroll
  for (int i4 = 0; i4 < 8; ++i4) {
    float4 ua = Ur[i4], ub = Ur[i4 + 8];
    float uav[4] = {ua.x, ua.y, ua.z, ua.w};
    float ubv[4] = {ub.x, ub.y, ub.z, ub.w};
#pragma unroll
    for (int t = 0; t < 4; ++t) {
      int i = i4 * 4 + t;
      D[i] = __fadd_rn(__fmul_rn(yn[i], uav[t]), __fmul_rn(yn[i + 32], ubv[t]));
    }
  }
#pragma unroll
  for (int i = 0; i < 16; ++i) D[i] = __fadd_rn(D[i], D[i + 16]);
#pragma unroll
  for (int i = 0; i < 8; ++i)  D[i] = __fadd_rn(D[i], D[i + 8]);
#pragma unroll
  for (int i = 0; i < 4; ++i)  D[i] = __fadd_rn(D[i], D[i + 4]);
#pragma unroll
  for (int i = 0; i < 2; ++i)  D[i] = __fadd_rn(D[i], D[i + 2]);
  float s = __fadd_rn(D[0], D[1]);
  score1_tail(s, lane, b, item, nb, nrel, out0, ap1_out, s1_idx, s1_rel, s1_ent,
              lmp1, wkg2);
}

__global__ __launch_bounds__(256) void k_score2(
    const int* __restrict__ users, const int* __restrict__ s1_rel,
    const float* __restrict__ U, const float* __restrict__ E,
    const int* __restrict__ allc, int* __restrict__ kept, int N) {
  int wid = threadIdx.x >> 6, lane = threadIdx.x & 63;
  int n = rfl(blockIdx.x * 4 + wid);
  if (n >= N) return;
  int b = n >> 2;
  int rel = rfl(s1_rel[n]);
  int usr = rfl(users[b]);
  int ent = allc[rel * 64 + lane];
  const float* ur = U + (size_t)usr * 64;
  const float4* e4 = reinterpret_cast<const float4*>(E + (size_t)ent * 64);
  float s = 0.f;
#pragma unroll
  for (int j4 = 0; j4 < 16; ++j4) {
    float4 t = e4[j4];
    s = fmaf(ur[4 * j4 + 0], t.x, s);
    s = fmaf(ur[4 * j4 + 1], t.y, s);
    s = fmaf(ur[4 * j4 + 2], t.z, s);
    s = fmaf(ur[4 * j4 + 3], t.w, s);
  }
  int rank = 0;
  for (int k2 = 0; k2 < 64; ++k2) {
    float sv = __shfl(s, k2);
    rank += (sv > s || (sv == s && k2 < lane)) ? 1 : 0;
  }
  if (rank < 32) kept[n * 32 + rank] = (lane << 18) | ent;
}

template <bool PERMQ>
__device__ __forceinline__ void sample_body(
    float q, int n, int b, int lane,
    const int* __restrict__ items, const int* __restrict__ s1_idx,
    int rel, const float* __restrict__ T2c, const int* __restrict__ kept,
    float* __restrict__ p2, int* __restrict__ wkg2) {
  int m = lane & 31;
  int pk = kept[n * 32 + m];
  int c = pk >> 18;
  int ent = pk & 0x3FFFF;
  const float4* c4 = reinterpret_cast<const float4*>(T2c + ((size_t)rel * 64 + c) * 64);
  float s = 0.f;
#pragma unroll
  for (int j4 = 0; j4 < 16; ++j4) {
    float4 t = c4[j4];
    s = fmaf(__shfl(q, PERMQ ? PERM_IDX(4 * j4 + 0) : (4 * j4 + 0)), t.x, s);
    s = fmaf(__shfl(q, PERMQ ? PERM_IDX(4 * j4 + 1) : (4 * j4 + 1)), t.y, s);
    s = fmaf(__shfl(q, PERMQ ? PERM_IDX(4 * j4 + 2) : (4 * j4 + 2)), t.z, s);
    s = fmaf(__shfl(q, PERMQ ? PERM_IDX(4 * j4 + 3) : (4 * j4 + 3)), t.w, s);
  }
  float mx = s;
#pragma unroll
  for (int off = 1; off < 32; off <<= 1) mx = fmaxf(mx, __shfl_xor(mx, off));
  float shv = s - mx;
  float se = expf(shv);
  float sum = se;
#pragma unroll
  for (int off = 1; off < 32; off <<= 1) sum += __shfl_xor(sum, off);
  float logp = shv - logf(sum);
  uint32_t h0, h1;
  threefry2x32(0u, 42u, 0u, (uint32_t)(n * 32 + m), h0, h1);
  uint32_t bits = h0 ^ h1;
  float u0 = __uint_as_float((bits >> 9) | 0x3F800000u) - 1.0f;
  float uu = fmaxf(u0, F32_TINY);
  float g = -logf(-logf(uu));
  float z = g + logp;
  float bz = z; int bm = m;
#pragma unroll
  for (int off = 1; off < 32; off <<= 1) {
    float oz = __shfl_xor(bz, off);
    int om = __shfl_xor(bm, off);
    if (oz > bz || (oz == bz && om < bm)) { bz = oz; bm = om; }
  }
  if (lane == bm) {
    p2[n] = expf(logp);
    int col = s1_idx[n];
    int item = items[b];
    atomicMax(&wkg2[(size_t)item * 64 + col], ((b + 1) << 18) | ent);
  }
}

__global__ __launch_bounds__(256) void k_sample(
    const int* __restrict__ items,
    const int* __restrict__ s1_idx, const int* __restrict__ s1_rel,
    const int* __restrict__ s1_ent,
    const float* __restrict__ E, const float* __restrict__ W1,
    const float* __restrict__ b1, const float* __restrict__ T2c,
    const float* __restrict__ uiE, const int* __restrict__ kept,
    float* __restrict__ p2, int* __restrict__ wkg2, int N) {
  __shared__ float Wl[4096];
  int tid = threadIdx.x;
  for (int i = tid; i < 4096; i += 256) Wl[i] = W1[i];
  __syncthreads();
  int wid = tid >> 6, lane = tid & 63;
  int n = rfl(blockIdx.x * 4 + wid);
  if (n >= N) return;
  int b = n >> 2;
  int rel = rfl(s1_rel[n]);
  int repl = rfl(s1_ent[n]);
  const float* er = E + (size_t)repl * 64;
  float y = 0.f;
#pragma unroll
  for (int k2 = 0; k2 < 64; ++k2) y = fmaf(er[k2], Wl[k2 * 64 + lane], y);
  y += b1[lane];
  float ss = y * y;
#pragma unroll
  for (int off = 32; off; off >>= 1) ss += __shfl_xor(ss, off);
  float yn = y / fmaxf(sqrtf(ss), EPS_NORM);
  float q = uiE[(size_t)b * 64 + lane] * yn;
  sample_body<false>(q, n, b, lane, items, s1_idx, rel, T2c, kept, p2, wkg2);
}

__global__ __launch_bounds__(256) void k_fin(const int* __restrict__ wkg2,
                                             const float* __restrict__ p2,
                                             const float* __restrict__ lmp1,
                                             float* __restrict__ out2,
                                             float* __restrict__ out3,
                                             int n, int B) {
  int i = blockIdx.x * 256 + threadIdx.x;
  if (i < n) out2[i] = (float)(wkg2[i] & 0x3FFFF);
  if (i < B) {
    float a = ((p2[i * 4] + p2[i * 4 + 1]) + p2[i * 4 + 2]) + p2[i * 4 + 3];
    out3[i] = lmp1[i] + logf(a * 0.25f);
  }
}

// -----------------------------------------------------------------------------
extern "C" void kernel_launch(void* const* d_in, const int* in_sizes, int n_in,
                              void* d_out, int out_size, void* d_ws, size_t ws_size,
                              hipStream_t stream) {
  const int*   users = (const int*)d_in[0];
  const int*   items = (const int*)d_in[1];
  const int*   kg    = (const int*)d_in[2];
  const int*   allc  = (const int*)d_in[3];
  const int*   nrel  = (const int*)d_in[4];
  const float* U     = (const float*)d_in[5];
  const float* E     = (const float*)d_in[6];
  const float* Iemb  = (const float*)d_in[7];
  const float* uiW   = (const float*)d_in[8];
  const float* uib   = (const float*)d_in[9];
  const float* e1W   = (const float*)d_in[10];
  const float* e1b   = (const float*)d_in[11];
  const float* e2W   = (const float*)d_in[12];
  const float* e2b   = (const float*)d_in[13];

  const int B = 4096, NCELL = 3200000, NCAND = 6400, NR4 = 16384, NENT = 200000;

  float* out0    = (float*)d_out;        // cf_kg1 [3.2M]
  float* out_ap1 = out0 + NCELL;         // ap1    [4096]
  float* out2    = out_ap1 + B;          // cf_kg2 [3.2M]
  float* out_ap2 = out2 + NCELL;         // ap2    [4096]

  float* T2c  = (float*)d_ws;            // 409,600 f
  float* uiE  = T2c + 409600;            // 262,144 f
  int*   wkg2 = (int*)(uiE + 262144);    // 3,200,000 i
  int*   s1i  = wkg2 + NCELL;            // 16384
  int*   s1r  = s1i + NR4;               // 16384
  int*   s1e  = s1r + NR4;               // 16384
  int*   kept = s1e + NR4;               // 524,288
  float* p2   = (float*)(kept + 524288); // 16384
  float* lmp1 = p2 + NR4;                // 4096
  float* T1   = lmp1 + B;                // 12,800,000 f (51.2 MB), path A only
  const size_t WS_NEED = ((size_t)(T1 + (size_t)NENT * 64) - (size_t)d_ws);
  const bool pathA = ws_size >= WS_NEED;

  if (pathA) {
    // phase1: T1 (782) + T2c (25) + ui (256) + init (200) = 1263 blocks
    k_phase1<<<1263, 256, 0, stream>>>(E, allc, e1W, e1b, e2W, e2b, U, users,
                                       Iemb, uiW, uib, kg, T1, T2c, uiE,
                                       out0, out2, wkg2);
    // fused step: cooperative phase A + dual-slot phases B/C
    k_step4<<<B / 4, 256, 0, stream>>>(items, users, kg, nrel, allc, E, T1, T2c,
                                       uiE, U, out0, out_ap1, s1i, lmp1, p2, wkg2);
    k_fin2<<<(NR4 + 255) / 256, 256, 0, stream>>>(items, s1i, wkg2, p2, lmp1,
                                                  out2, out_ap2, NR4, B);
  } else {
    k_init<<<(NCELL + 255) / 256, 256, 0, stream>>>(kg, out0, wkg2, NCELL);
    k_ui<<<(B + 3) / 4, 256, 0, stream>>>(U, users, Iemb, uiW, uib, uiE, B);
    k_transform64<<<(NCAND + 3) / 4, 256, 0, stream>>>(E, allc, e2W, e2b, T2c, NCAND);
    k_score1<<<B / 4, 256, 0, stream>>>(items, kg, nrel, E, e1W, e1b, uiE,
                                        out0, out_ap1, s1i, s1r, s1e, lmp1, wkg2);
    k_score2<<<(NR4 + 3) / 4, 256, 0, stream>>>(users, s1r, U, E, allc, kept, NR4);
    k_sample<<<(NR4 + 3) / 4, 256, 0, stream>>>(items, s1i, s1r, s1e, E, e1W, e1b,
                                                T2c, uiE, kept, p2, wkg2, NR4);
    k_fin<<<(NCELL + 255) / 256, 256, 0, stream>>>(wkg2, p2, lmp1, out2, out_ap2,
                                                   NCELL, B);
  }
}

// Round 20
// 127.784 us; speedup vs baseline: 1.3653x; 1.3653x over previous
//
#include <hip/hip_runtime.h>
#include <stdint.h>

#define EPS_NORM 1e-12f
#define F32_TINY 1.17549435e-38f

static __device__ __forceinline__ int rfl(int v) {
  return __builtin_amdgcn_readfirstlane(v);
}

// ---------------- Threefry2x32 (exact JAX replica, 20 rounds) ----------------
__device__ __forceinline__ void threefry2x32(uint32_t k0, uint32_t k1,
                                             uint32_t x0, uint32_t x1,
                                             uint32_t& o0, uint32_t& o1) {
  uint32_t ks2 = k0 ^ k1 ^ 0x1BD11BDAu;
  x0 += k0; x1 += k1;
#define TF_ROT(r) { x0 += x1; x1 = (x1 << (r)) | (x1 >> (32 - (r))); x1 ^= x0; }
  TF_ROT(13) TF_ROT(15) TF_ROT(26) TF_ROT(6)
  x0 += k1; x1 += ks2 + 1u;
  TF_ROT(17) TF_ROT(29) TF_ROT(16) TF_ROT(24)
  x0 += ks2; x1 += k0 + 2u;
  TF_ROT(13) TF_ROT(15) TF_ROT(26) TF_ROT(6)
  x0 += k0; x1 += k1 + 3u;
  TF_ROT(17) TF_ROT(29) TF_ROT(16) TF_ROT(24)
  x0 += k1; x1 += ks2 + 4u;
  TF_ROT(13) TF_ROT(15) TF_ROT(26) TF_ROT(6)
  x0 += ks2; x1 += k0 + 5u;
#undef TF_ROT
  o0 = x0; o1 = x1;
}

// P(p) = (p&7)*8 + (p>>3): involution used for T1's coalesced permuted layout.
#define PERM_IDX(p) ((((p) & 7) << 3) | ((p) >> 3))

// ========== PHASE 1 mega-kernel: T1 + T2c + ui + init ========================
// Roles: [0,782) T1, [782,807) T2c, [807,1063) ui, [1063,1263) init.
// (verbatim R16/R18: conflicts 0; init role zeroes wkg2 for k_step4)
__global__ __launch_bounds__(256) void k_phase1(
    const float* __restrict__ E, const int* __restrict__ allc,
    const float* __restrict__ W1, const float* __restrict__ b1,
    const float* __restrict__ W2, const float* __restrict__ b2,
    const float* __restrict__ U, const int* __restrict__ users,
    const float* __restrict__ Iemb, const float* __restrict__ uiW,
    const float* __restrict__ uib, const int* __restrict__ kg,
    float* __restrict__ T1, float* __restrict__ T2c,
    float* __restrict__ uiE, float* __restrict__ out0, float* __restrict__ out2,
    int* __restrict__ wkg2) {
  __shared__ float SM[8192];
  const int blk = blockIdx.x, tid = threadIdx.x;
  const int wv = tid >> 6, lane = tid & 63;
  const int NT1B = 782, NT2B = 25, NUIB = 256;
  if (blk < NT1B + NT2B) {
    const bool isT1 = blk < NT1B;
    {
      const float* W = isT1 ? W1 : W2;
      for (int idx = tid; idx < 4096; idx += 256) {
        int k = idx >> 6, c = idx & 63;
        int cg = c & 7, ci = c >> 3;
        SM[k * 64 + ((ci >> 2) * 8 + cg) * 4 + (ci & 3)] = W[idx];
      }
    }
    __syncthreads();
    const int rg = lane >> 3, cg = lane & 7;
    const int sub = lane >> 5, r = lane & 31;
    const float* bias = isT1 ? b1 : b2;
    float bv[8];
#pragma unroll
    for (int ci = 0; ci < 8; ++ci) bv[ci] = bias[ci * 8 + cg];
    float* eTw = SM + 4096 + wv * 1024;
    const float4* eT4 = reinterpret_cast<const float4*>(eTw);
    const float4* W4 = reinterpret_cast<const float4*>(SM);
#pragma unroll 1
    for (int t = 0; t < 2; ++t) {
      int batch = (isT1 ? blk : blk - NT1B) * 2 + t;
      int rbase = batch * 128 + wv * 32;
      if (isT1 && rbase >= 200000) continue;
      int srow = isT1 ? (rbase + r) : allc[rbase + r];
      const float4* Er = reinterpret_cast<const float4*>(E + (size_t)srow * 64);
      float4 a0 = Er[sub * 4 + 0], a1 = Er[sub * 4 + 1];
      float4 a2 = Er[sub * 4 + 2], a3 = Er[sub * 4 + 3];
      float4 a4 = Er[8 + sub * 4 + 0], a5 = Er[8 + sub * 4 + 1];
      float4 a6 = Er[8 + sub * 4 + 2], a7 = Er[8 + sub * 4 + 3];
      float y[4][8];
#pragma unroll
      for (int ri = 0; ri < 4; ++ri)
#pragma unroll
        for (int ci = 0; ci < 8; ++ci) y[ri][ci] = 0.f;
      {
        float ev[16] = {a0.x, a0.y, a0.z, a0.w, a1.x, a1.y, a1.z, a1.w,
                        a2.x, a2.y, a2.z, a2.w, a3.x, a3.y, a3.z, a3.w};
#pragma unroll
        for (int kk = 0; kk < 16; ++kk)
          eTw[(sub * 16 + kk) * 32 + r] = ev[kk];
#pragma unroll 8
        for (int kk = 0; kk < 32; ++kk) {
          float4 e4 = eT4[kk * 8 + rg];
          float4 wa = W4[kk * 16 + cg];
          float4 wb = W4[kk * 16 + 8 + cg];
          float ev4[4] = {e4.x, e4.y, e4.z, e4.w};
          float wv8[8] = {wa.x, wa.y, wa.z, wa.w, wb.x, wb.y, wb.z, wb.w};
#pragma unroll
          for (int ri = 0; ri < 4; ++ri)
#pragma unroll
            for (int ci = 0; ci < 8; ++ci)
              y[ri][ci] = fmaf(ev4[ri], wv8[ci], y[ri][ci]);
        }
      }
      {
        float ev[16] = {a4.x, a4.y, a4.z, a4.w, a5.x, a5.y, a5.z, a5.w,
                        a6.x, a6.y, a6.z, a6.w, a7.x, a7.y, a7.z, a7.w};
#pragma unroll
        for (int kk = 0; kk < 16; ++kk)
          eTw[(sub * 16 + kk) * 32 + r] = ev[kk];
#pragma unroll 8
        for (int kk = 0; kk < 32; ++kk) {
          float4 e4 = eT4[kk * 8 + rg];
          float4 wa = W4[(32 + kk) * 16 + cg];
          float4 wb = W4[(32 + kk) * 16 + 8 + cg];
          float ev4[4] = {e4.x, e4.y, e4.z, e4.w};
          float wv8[8] = {wa.x, wa.y, wa.z, wa.w, wb.x, wb.y, wb.z, wb.w};
#pragma unroll
          for (int ri = 0; ri < 4; ++ri)
#pragma unroll
            for (int ci = 0; ci < 8; ++ci)
              y[ri][ci] = fmaf(ev4[ri], wv8[ci], y[ri][ci]);
        }
      }
#pragma unroll
      for (int ri = 0; ri < 4; ++ri)
#pragma unroll
        for (int ci = 0; ci < 8; ++ci)
          y[ri][ci] = __fadd_rn(y[ri][ci], bv[ci]);
#pragma unroll
      for (int ri = 0; ri < 4; ++ri) {
        float A0 = __fadd_rn(__fmul_rn(y[ri][0], y[ri][0]),
                             __fmul_rn(y[ri][4], y[ri][4]));
        float A1 = __fadd_rn(__fmul_rn(y[ri][1], y[ri][1]),
                             __fmul_rn(y[ri][5], y[ri][5]));
        float A2 = __fadd_rn(__fmul_rn(y[ri][2], y[ri][2]),
                             __fmul_rn(y[ri][6], y[ri][6]));
        float A3 = __fadd_rn(__fmul_rn(y[ri][3], y[ri][3]),
                             __fmul_rn(y[ri][7], y[ri][7]));
        float B0 = __fadd_rn(A0, A2), B1 = __fadd_rn(A1, A3);
        float C = __fadd_rn(B0, B1);
        C = __fadd_rn(C, __shfl_xor(C, 4));
        C = __fadd_rn(C, __shfl_xor(C, 2));
        C = __fadd_rn(C, __shfl_xor(C, 1));
        float denom = fmaxf(sqrtf(C), EPS_NORM);
        int row = rbase + rg * 4 + ri;
        if (isT1) {
          float4* drow = reinterpret_cast<float4*>(T1 + (size_t)row * 64 + cg * 8);
          drow[0] = make_float4(y[ri][0] / denom, y[ri][1] / denom,
                                y[ri][2] / denom, y[ri][3] / denom);
          drow[1] = make_float4(y[ri][4] / denom, y[ri][5] / denom,
                                y[ri][6] / denom, y[ri][7] / denom);
        } else {
          float* drow = T2c + (size_t)row * 64;
#pragma unroll
          for (int ci = 0; ci < 8; ++ci) drow[ci * 8 + cg] = y[ri][ci] / denom;
        }
      }
    }
  } else if (blk < NT1B + NT2B + NUIB) {
    int ub = blk - (NT1B + NT2B);
    for (int i = tid; i < 8192; i += 256) SM[i] = uiW[i];
    __syncthreads();
    float bl = uib[lane];
#pragma unroll 1
    for (int t = 0; t < 4; ++t) {
      int b = ub * 16 + wv * 4 + t;
      int usr = rfl(users[b]);
      const float* ur = U + (size_t)usr * 64;
      const float* ir = Iemb + (size_t)b * 64;
      float y = 0.f;
#pragma unroll
      for (int k = 0; k < 64; ++k) y = fmaf(ur[k], SM[k * 64 + lane], y);
#pragma unroll
      for (int k = 0; k < 64; ++k) y = fmaf(ir[k], SM[(64 + k) * 64 + lane], y);
      y += bl;
      float ss = y * y;
#pragma unroll
      for (int off = 32; off; off >>= 1) ss += __shfl_xor(ss, off);
      float yn = y / fmaxf(sqrtf(ss), EPS_NORM);
      uiE[(size_t)b * 64 + lane] = yn;
    }
  } else {
    const int4* kg4 = reinterpret_cast<const int4*>(kg);
    float4* o4 = reinterpret_cast<float4*>(out0);
    float4* o24 = reinterpret_cast<float4*>(out2);
    int4* wz = reinterpret_cast<int4*>(wkg2);
    int4 z; z.x = 0; z.y = 0; z.z = 0; z.w = 0;
    for (int i = (blk - 1063) * 256 + tid; i < 800000; i += 200 * 256) {
      int4 v = kg4[i];
      float4 f = make_float4((float)v.x, (float)v.y, (float)v.z, (float)v.w);
      o4[i] = f;
      o24[i] = f;
      wz[i] = z;
    }
  }
}

// ====== FUSED STEP4 (path A): score1+score2+sample; 4 items/block ============
// Phase A: 4-lane cooperative T1 gather (each instruction reads contiguous
// 64B per group -> 4x fewer line requests); D-tree remapped EXACTLY onto the
// lane split (stage-0 = shfl_xor(1), folds in-lane, final = shfl_xor(2)).
// Phases B+C: verbatim R12/R16 bodies. (R18 configuration — measured best.)
__global__ __launch_bounds__(256) void k_step4(
    const int* __restrict__ items, const int* __restrict__ users,
    const int* __restrict__ kg, const int* __restrict__ nrel,
    const int* __restrict__ allc, const float* __restrict__ E,
    const float* __restrict__ T1, const float* __restrict__ T2c,
    const float* __restrict__ uiE, const float* __restrict__ U,
    float* __restrict__ out0, float* __restrict__ ap1_out,
    int* __restrict__ s1i_g, float* __restrict__ lmp1,
    float* __restrict__ p2, int* __restrict__ wkg2) {
  __shared__ int s1_idx_sh[4][4], s1_rel_sh[4][4], s1_ent_sh[4][4];
  __shared__ int kept_sh[4][32];
  __shared__ float scoreA[4][64];
  const int tid = threadIdx.x, wv = tid >> 6, lane = tid & 63;
  const int blk = blockIdx.x;
  // ---------------- phase A: cooperative score1 ----------------------------
  {
    const int b = blk * 4 + wv;
    const int item = rfl(items[b]);
    int nbAll = kg[(size_t)item * 64 + lane];
    const int g = lane >> 2, q = lane & 3;
    // lane's logical columns: j(f,e) = ((q&1)?32:0) + 8e + 2f + (q>>1)
    float uu[4][4];
#pragma unroll
    for (int f = 0; f < 4; ++f)
#pragma unroll
      for (int e = 0; e < 4; ++e) {
        int j = ((q & 1) << 5) + 8 * e + 2 * f + ((q >> 1) & 1);
        uu[f][e] = uiE[(size_t)b * 64 + j];
      }
#pragma unroll 1
    for (int pass = 0; pass < 4; ++pass) {
      int rowIdx = pass * 16 + g;
      int nbr = __shfl(nbAll, rowIdx);
      const float4* R = reinterpret_cast<const float4*>(T1 + (size_t)nbr * 64);
      float4 v0 = R[q], v1 = R[4 + q], v2 = R[8 + q], v3 = R[12 + q];
      float vv[4][4] = {{v0.x, v0.y, v0.z, v0.w}, {v1.x, v1.y, v1.z, v1.w},
                        {v2.x, v2.y, v2.z, v2.w}, {v3.x, v3.y, v3.z, v3.w}};
      // products yn[j]*ui[j] (verbatim operand pair of the original tree)
      float pr[4][4];  // pr[e][f]
#pragma unroll
      for (int f = 0; f < 4; ++f)
#pragma unroll
        for (int e = 0; e < 4; ++e)
          pr[e][f] = __fmul_rn(vv[f][e], uu[f][e]);
      // stage0: D[i] = (yn[i]*ui[i]) + (yn[i+32]*ui[i+32])  -> lane^1
      float dd[4][4];
#pragma unroll
      for (int e = 0; e < 4; ++e)
#pragma unroll
        for (int f = 0; f < 4; ++f)
          dd[e][f] = __fadd_rn(pr[e][f], __shfl_xor(pr[e][f], 1));
      // stage1 (+16): e pairs (0,2),(1,3)
#pragma unroll
      for (int f = 0; f < 4; ++f) {
        dd[0][f] = __fadd_rn(dd[0][f], dd[2][f]);
        dd[1][f] = __fadd_rn(dd[1][f], dd[3][f]);
      }
      // stage2 (+8): e pairs (0,1)
#pragma unroll
      for (int f = 0; f < 4; ++f)
        dd[0][f] = __fadd_rn(dd[0][f], dd[1][f]);
      // stage3 (+4): f pairs (0,2),(1,3)
      float t0 = __fadd_rn(dd[0][0], dd[0][2]);
      float t1 = __fadd_rn(dd[0][1], dd[0][3]);
      // stage4 (+2)
      float uh = __fadd_rn(t0, t1);
      // final: even half + odd half -> lane^2
      float sF = __fadd_rn(uh, __shfl_xor(uh, 2));
      if (q == 0) scoreA[wv][rowIdx] = sF;
    }
    float s = scoreA[wv][lane];     // same-wave LDS dep (lgkmcnt)
    int nb = nbAll;
    // ---- verbatim softmax/rank/top4 tail ----
    float m = s;
#pragma unroll
    for (int off = 32; off; off >>= 1) m = fmaxf(m, __shfl_xor(m, off));
    float ex = expf(s - m);
    float sum = ex;
#pragma unroll
    for (int off = 32; off; off >>= 1) sum += __shfl_xor(sum, off);
    float p = ex / sum;
    int rank = 0;
    for (int k2 = 0; k2 < 64; ++k2) {
      float pv = __shfl(p, k2);
      rank += (pv > p || (pv == p && k2 < lane)) ? 1 : 0;
    }
    float acc = 0.f;
#pragma unroll
    for (int rr = 0; rr < 4; ++rr) {
      unsigned long long msk = __ballot(rank == rr);
      int src = __ffsll(msk) - 1;
      acc += __shfl(p, src);
    }
    float lm = logf(acc * 0.25f);
    if (lane == 0) { ap1_out[b] = lm; lmp1[b] = lm; }
    if (rank < 4) {
      s1_idx_sh[wv][rank] = lane;
      s1_ent_sh[wv][rank] = nb;
      s1_rel_sh[wv][rank] = nrel[(size_t)item * 64 + lane];
      s1i_g[b * 4 + rank] = lane;
      out0[(size_t)item * 64 + lane] = 0.0f;
      // wkg2 zeroed in k_phase1 init role (in-kernel zero would race)
    }
  }
  __syncthreads();
  // ---------------- phases B + C: 4 slot-rounds, verbatim R16 bodies --------
#pragma unroll 1
  for (int slot = 0; slot < 4; ++slot) {
    const int b = blk * 4 + slot;
    const int item = rfl(items[b]);
    const int n = b * 4 + wv;
    const int rel = rfl(s1_rel_sh[slot][wv]);
    const int repl = rfl(s1_ent_sh[slot][wv]);
    const int colsel = rfl(s1_idx_sh[slot][wv]);
    // ---- phase B: score2 (verbatim) ----
    {
      int usr = rfl(users[b]);
      int ent = allc[rel * 64 + lane];
      const float* ur = U + (size_t)usr * 64;
      const float4* e4 = reinterpret_cast<const float4*>(E + (size_t)ent * 64);
      float s = 0.f;
#pragma unroll
      for (int j4 = 0; j4 < 16; ++j4) {
        float4 t = e4[j4];
        s = fmaf(ur[4 * j4 + 0], t.x, s);
        s = fmaf(ur[4 * j4 + 1], t.y, s);
        s = fmaf(ur[4 * j4 + 2], t.z, s);
        s = fmaf(ur[4 * j4 + 3], t.w, s);
      }
      int rank = 0;
      for (int k2 = 0; k2 < 64; ++k2) {
        float sv = __shfl(s, k2);
        rank += (sv > s || (sv == s && k2 < lane)) ? 1 : 0;
      }
      if (rank < 32) kept_sh[wv][rank] = (lane << 18) | ent;
    }
    // ---- phase C: sample (verbatim sample_body<true> with LDS kept) ----
    {
      int m = lane & 31;
      int pk = kept_sh[wv][m];            // same-wave LDS dep
      int c = pk >> 18;
      int ent = pk & 0x3FFFF;
      float q = uiE[(size_t)b * 64 + PERM_IDX(lane)] *
                T1[(size_t)repl * 64 + lane];
      const float4* c4 = reinterpret_cast<const float4*>(
          T2c + ((size_t)rel * 64 + c) * 64);
      float s = 0.f;
#pragma unroll
      for (int j4 = 0; j4 < 16; ++j4) {
        float4 t = c4[j4];
        s = fmaf(__shfl(q, PERM_IDX(4 * j4 + 0)), t.x, s);
        s = fmaf(__shfl(q, PERM_IDX(4 * j4 + 1)), t.y, s);
        s = fmaf(__shfl(q, PERM_IDX(4 * j4 + 2)), t.z, s);
        s = fmaf(__shfl(q, PERM_IDX(4 * j4 + 3)), t.w, s);
      }
      float mx = s;
#pragma unroll
      for (int off = 1; off < 32; off <<= 1) mx = fmaxf(mx, __shfl_xor(mx, off));
      float shv = s - mx;
      float se = expf(shv);
      float sum = se;
#pragma unroll
      for (int off = 1; off < 32; off <<= 1) sum += __shfl_xor(sum, off);
      float logp = shv - logf(sum);
      uint32_t h0, h1;
      threefry2x32(0u, 42u, 0u, (uint32_t)(n * 32 + m), h0, h1);
      uint32_t bits = h0 ^ h1;
      float u0 = __uint_as_float((bits >> 9) | 0x3F800000u) - 1.0f;
      float uu2 = fmaxf(u0, F32_TINY);
      float g = -logf(-logf(uu2));
      float z = g + logp;
      float bz = z; int bm = m;
#pragma unroll
      for (int off = 1; off < 32; off <<= 1) {
        float oz = __shfl_xor(bz, off);
        int om = __shfl_xor(bm, off);
        if (oz > bz || (oz == bz && om < bm)) { bz = oz; bm = om; }
      }
      if (lane == bm) {
        p2[n] = expf(logp);
        atomicMax(&wkg2[(size_t)item * 64 + colsel], ((b + 1) << 18) | ent);
      }
    }
  }
}

// --------- finalize (path A): patch 16K cells of out2 + ap2 ------------------
__global__ __launch_bounds__(256) void k_fin2(
    const int* __restrict__ items, const int* __restrict__ s1_idx,
    const int* __restrict__ wkg2, const float* __restrict__ p2,
    const float* __restrict__ lmp1,
    float* __restrict__ out2, float* __restrict__ out3, int N, int B) {
  int i = blockIdx.x * 256 + threadIdx.x;
  if (i < N) {
    int b = i >> 2;
    int item = items[b];
    int col = s1_idx[i];
    int v = wkg2[(size_t)item * 64 + col];
    out2[(size_t)item * 64 + col] = (float)(v & 0x3FFFF);
  }
  if (i < B) {
    float a = ((p2[i * 4] + p2[i * 4 + 1]) + p2[i * 4 + 2]) + p2[i * 4 + 3];
    out3[i] = lmp1[i] + logf(a * 0.25f);
  }
}

// ================= fallback-path kernels (path B, unchanged) =================
__global__ __launch_bounds__(256) void k_init(const int* __restrict__ kg,
                                              float* __restrict__ out0,
                                              int* __restrict__ wkg2, int n) {
  int i = blockIdx.x * 256 + threadIdx.x;
  if (i < n) { int v = kg[i]; out0[i] = (float)v; wkg2[i] = v; }
}

__device__ __forceinline__ void transform_row(const float4* __restrict__ Er,
                                              const float* __restrict__ W,
                                              const float* __restrict__ bias,
                                              float (&yn)[64]) {
  float y[64];
#pragma unroll
  for (int j = 0; j < 64; ++j) y[j] = 0.f;
  float4 c0 = Er[0], c1 = Er[1], c2 = Er[2], c3 = Er[3];
#pragma unroll 1
  for (int cc = 0; cc < 4; ++cc) {
    float4 n0, n1, n2, n3;
    if (cc < 3) { n0 = Er[cc * 4 + 4]; n1 = Er[cc * 4 + 5];
                  n2 = Er[cc * 4 + 6]; n3 = Er[cc * 4 + 7]; }
    float ev[16] = {c0.x, c0.y, c0.z, c0.w, c1.x, c1.y, c1.z, c1.w,
                    c2.x, c2.y, c2.z, c2.w, c3.x, c3.y, c3.z, c3.w};
#pragma unroll
    for (int k2i = 0; k2i < 16; ++k2i) {
      const float4* Wr = reinterpret_cast<const float4*>(
          W + ((size_t)(cc * 16 + k2i)) * 64);
      float ek = ev[k2i];
#pragma unroll
      for (int j4 = 0; j4 < 16; ++j4) {
        float4 w = Wr[j4];
        y[j4 * 4 + 0] = fmaf(ek, w.x, y[j4 * 4 + 0]);
        y[j4 * 4 + 1] = fmaf(ek, w.y, y[j4 * 4 + 1]);
        y[j4 * 4 + 2] = fmaf(ek, w.z, y[j4 * 4 + 2]);
        y[j4 * 4 + 3] = fmaf(ek, w.w, y[j4 * 4 + 3]);
      }
    }
    c0 = n0; c1 = n1; c2 = n2; c3 = n3;
  }
  const float4* B4 = reinterpret_cast<const float4*>(bias);
#pragma unroll
  for (int j4 = 0; j4 < 16; ++j4) {
    float4 bb = B4[j4];
    float bv[4] = {bb.x, bb.y, bb.z, bb.w};
#pragma unroll
    for (int t = 0; t < 4; ++t) y[j4 * 4 + t] = __fadd_rn(y[j4 * 4 + t], bv[t]);
  }
  float S1[32];
#pragma unroll
  for (int i = 0; i < 32; ++i)
    S1[i] = __fadd_rn(__fmul_rn(y[i], y[i]), __fmul_rn(y[i + 32], y[i + 32]));
#pragma unroll
  for (int i = 0; i < 16; ++i) S1[i] = __fadd_rn(S1[i], S1[i + 16]);
#pragma unroll
  for (int i = 0; i < 8; ++i)  S1[i] = __fadd_rn(S1[i], S1[i + 8]);
#pragma unroll
  for (int i = 0; i < 4; ++i)  S1[i] = __fadd_rn(S1[i], S1[i + 4]);
#pragma unroll
  for (int i = 0; i < 2; ++i)  S1[i] = __fadd_rn(S1[i], S1[i + 2]);
  float ss = __fadd_rn(S1[0], S1[1]);
  float denom = fmaxf(sqrtf(ss), EPS_NORM);
#pragma unroll
  for (int j = 0; j < 64; ++j) yn[j] = y[j] / denom;
}

__global__ __launch_bounds__(256) void k_transform64(
    const float* __restrict__ src, const int* __restrict__ gidx,
    const float* __restrict__ W, const float* __restrict__ bias,
    float* __restrict__ out, int nrows) {
  __shared__ float Wl[4096];
  for (int i = threadIdx.x; i < 4096; i += 256) Wl[i] = W[i];
  __syncthreads();
  int wid = threadIdx.x >> 6, lane = threadIdx.x & 63;
  int row = rfl(blockIdx.x * 4 + wid);
  if (row >= nrows) return;
  int srow = rfl(gidx ? gidx[row] : row);
  const float* er = src + (size_t)srow * 64;
  float y = 0.f;
#pragma unroll
  for (int k = 0; k < 64; ++k) y = fmaf(er[k], Wl[k * 64 + lane], y);
  y += bias[lane];
  float ss = y * y;
#pragma unroll
  for (int off = 32; off; off >>= 1) ss += __shfl_xor(ss, off);
  float yn = y / fmaxf(sqrtf(ss), EPS_NORM);
  out[(size_t)row * 64 + lane] = yn;
}

__global__ __launch_bounds__(256) void k_ui(
    const float* __restrict__ U, const int* __restrict__ users,
    const float* __restrict__ Iemb, const float* __restrict__ W,
    const float* __restrict__ bias, float* __restrict__ out, int B) {
  __shared__ float Wl[8192];
  for (int i = threadIdx.x; i < 8192; i += 256) Wl[i] = W[i];
  __syncthreads();
  int wid = threadIdx.x >> 6, lane = threadIdx.x & 63;
  int b = rfl(blockIdx.x * 4 + wid);
  if (b >= B) return;
  int usr = rfl(users[b]);
  const float* ur = U + (size_t)usr * 64;
  const float* ir = Iemb + (size_t)b * 64;
  float y = 0.f;
#pragma unroll
  for (int k = 0; k < 64; ++k) y = fmaf(ur[k], Wl[k * 64 + lane], y);
#pragma unroll
  for (int k = 0; k < 64; ++k) y = fmaf(ir[k], Wl[(64 + k) * 64 + lane], y);
  y += bias[lane];
  float ss = y * y;
#pragma unroll
  for (int off = 32; off; off >>= 1) ss += __shfl_xor(ss, off);
  float yn = y / fmaxf(sqrtf(ss), EPS_NORM);
  out[(size_t)b * 64 + lane] = yn;
}

__device__ __forceinline__ void score1_tail(
    float s, int lane, int b, int item, int nb,
    const int* __restrict__ nrel,
    float* __restrict__ out0, float* __restrict__ ap1_out,
    int* __restrict__ s1_idx, int* __restrict__ s1_rel, int* __restrict__ s1_ent,
    float* __restrict__ lmp1, int* __restrict__ wkg2) {
  float m = s;
#pragma unroll
  for (int off = 32; off; off >>= 1) m = fmaxf(m, __shfl_xor(m, off));
  float ex = expf(s - m);
  float sum = ex;
#pragma unroll
  for (int off = 32; off; off >>= 1) sum += __shfl_xor(sum, off);
  float p = ex / sum;
  int rank = 0;
  for (int k2 = 0; k2 < 64; ++k2) {
    float pv = __shfl(p, k2);
    rank += (pv > p || (pv == p && k2 < lane)) ? 1 : 0;
  }
  float acc = 0.f;
#pragma unroll
  for (int rr = 0; rr < 4; ++rr) {
    unsigned long long msk = __ballot(rank == rr);
    int src = __ffsll(msk) - 1;
    acc += __shfl(p, src);
  }
  float lm = logf(acc * 0.25f);
  if (lane == 0) { ap1_out[b] = lm; lmp1[b] = lm; }
  if (rank < 4) {
    s1_idx[b * 4 + rank] = lane;
    s1_ent[b * 4 + rank] = nb;
    s1_rel[b * 4 + rank] = nrel[(size_t)item * 64 + lane];
    out0[(size_t)item * 64 + lane] = 0.0f;
    wkg2[(size_t)item * 64 + lane] = 0;
  }
}

__global__ __launch_bounds__(256) void k_score1(
    const int* __restrict__ items, const int* __restrict__ kg,
    const int* __restrict__ nrel, const float* __restrict__ E,
    const float* __restrict__ W1, const float* __restrict__ b1,
    const float* __restrict__ uiE,
    float* __restrict__ out0, float* __restrict__ ap1_out,
    int* __restrict__ s1_idx, int* __restrict__ s1_rel, int* __restrict__ s1_ent,
    float* __restrict__ lmp1, int* __restrict__ wkg2) {
  int tid = threadIdx.x, wv = tid >> 6, lane = tid & 63;
  int b = rfl(blockIdx.x * 4 + wv);
  int item = rfl(items[b]);
  int nb = kg[(size_t)item * 64 + lane];
  const float4* Er = reinterpret_cast<const float4*>(E + (size_t)nb * 64);
  float yn[64];
  transform_row(Er, W1, b1, yn);
  const float4* Ur = reinterpret_cast<const float4*>(uiE + (size_t)b * 64);
  float D[32];
#pragma unroll
  for (int i4 = 0; i4 < 8; ++i4) {
    float4 ua = Ur[i4], ub = Ur[i4 + 8];
    float uav[4] = {ua.x, ua.y, ua.z, ua.w};
    float ubv[4] = {ub.x, ub.y, ub.z, ub.w};
#pragma unroll
    for (int t = 0; t < 4; ++t) {
      int i = i4 * 4 + t;
      D[i] = __fadd_rn(__fmul_rn(yn[i], uav[t]), __fmul_rn(yn[i + 32], ubv[t]));
    }
  }
#pragma unroll
  for (int i = 0; i < 16; ++i) D[i] = __fadd_rn(D[i], D[i + 16]);
#pragma unroll
  for (int i = 0; i < 8; ++i)  D[i] = __fadd_rn(D[i], D[i + 8]);
#pragma unroll
  for (int i = 0; i < 4; ++i)  D[i] = __fadd_rn(D[i], D[i + 4]);
#pragma unroll
  for (int i = 0; i < 2; ++i)  D[i] = __fadd_rn(D[i], D[i + 2]);
  float s = __fadd_rn(D[0], D[1]);
  score1_tail(s, lane, b, item, nb, nrel, out0, ap1_out, s1_idx, s1_rel, s1_ent,
              lmp1, wkg2);
}

__global__ __launch_bounds__(256) void k_score2(
    const int* __restrict__ users, const int* __restrict__ s1_rel,
    const float* __restrict__ U, const float* __restrict__ E,
    const int* __restrict__ allc, int* __restrict__ kept, int N) {
  int wid = threadIdx.x >> 6, lane = threadIdx.x & 63;
  int n = rfl(blockIdx.x * 4 + wid);
  if (n >= N) return;
  int b = n >> 2;
  int rel = rfl(s1_rel[n]);
  int usr = rfl(users[b]);
  int ent = allc[rel * 64 + lane];
  const float* ur = U + (size_t)usr * 64;
  const float4* e4 = reinterpret_cast<const float4*>(E + (size_t)ent * 64);
  float s = 0.f;
#pragma unroll
  for (int j4 = 0; j4 < 16; ++j4) {
    float4 t = e4[j4];
    s = fmaf(ur[4 * j4 + 0], t.x, s);
    s = fmaf(ur[4 * j4 + 1], t.y, s);
    s = fmaf(ur[4 * j4 + 2], t.z, s);
    s = fmaf(ur[4 * j4 + 3], t.w, s);
  }
  int rank = 0;
  for (int k2 = 0; k2 < 64; ++k2) {
    float sv = __shfl(s, k2);
    rank += (sv > s || (sv == s && k2 < lane)) ? 1 : 0;
  }
  if (rank < 32) kept[n * 32 + rank] = (lane << 18) | ent;
}

template <bool PERMQ>
__device__ __forceinline__ void sample_body(
    float q, int n, int b, int lane,
    const int* __restrict__ items, const int* __restrict__ s1_idx,
    int rel, const float* __restrict__ T2c, const int* __restrict__ kept,
    float* __restrict__ p2, int* __restrict__ wkg2) {
  int m = lane & 31;
  int pk = kept[n * 32 + m];
  int c = pk >> 18;
  int ent = pk & 0x3FFFF;
  const float4* c4 = reinterpret_cast<const float4*>(T2c + ((size_t)rel * 64 + c) * 64);
  float s = 0.f;
#pragma unroll
  for (int j4 = 0; j4 < 16; ++j4) {
    float4 t = c4[j4];
    s = fmaf(__shfl(q, PERMQ ? PERM_IDX(4 * j4 + 0) : (4 * j4 + 0)), t.x, s);
    s = fmaf(__shfl(q, PERMQ ? PERM_IDX(4 * j4 + 1) : (4 * j4 + 1)), t.y, s);
    s = fmaf(__shfl(q, PERMQ ? PERM_IDX(4 * j4 + 2) : (4 * j4 + 2)), t.z, s);
    s = fmaf(__shfl(q, PERMQ ? PERM_IDX(4 * j4 + 3) : (4 * j4 + 3)), t.w, s);
  }
  float mx = s;
#pragma unroll
  for (int off = 1; off < 32; off <<= 1) mx = fmaxf(mx, __shfl_xor(mx, off));
  float shv = s - mx;
  float se = expf(shv);
  float sum = se;
#pragma unroll
  for (int off = 1; off < 32; off <<= 1) sum += __shfl_xor(sum, off);
  float logp = shv - logf(sum);
  uint32_t h0, h1;
  threefry2x32(0u, 42u, 0u, (uint32_t)(n * 32 + m), h0, h1);
  uint32_t bits = h0 ^ h1;
  float u0 = __uint_as_float((bits >> 9) | 0x3F800000u) - 1.0f;
  float uu = fmaxf(u0, F32_TINY);
  float g = -logf(-logf(uu));
  float z = g + logp;
  float bz = z; int bm = m;
#pragma unroll
  for (int off = 1; off < 32; off <<= 1) {
    float oz = __shfl_xor(bz, off);
    int om = __shfl_xor(bm, off);
    if (oz > bz || (oz == bz && om < bm)) { bz = oz; bm = om; }
  }
  if (lane == bm) {
    p2[n] = expf(logp);
    int col = s1_idx[n];
    int item = items[b];
    atomicMax(&wkg2[(size_t)item * 64 + col], ((b + 1) << 18) | ent);
  }
}

__global__ __launch_bounds__(256) void k_sample(
    const int* __restrict__ items,
    const int* __restrict__ s1_idx, const int* __restrict__ s1_rel,
    const int* __restrict__ s1_ent,
    const float* __restrict__ E, const float* __restrict__ W1,
    const float* __restrict__ b1, const float* __restrict__ T2c,
    const float* __restrict__ uiE, const int* __restrict__ kept,
    float* __restrict__ p2, int* __restrict__ wkg2, int N) {
  __shared__ float Wl[4096];
  int tid = threadIdx.x;
  for (int i = tid; i < 4096; i += 256) Wl[i] = W1[i];
  __syncthreads();
  int wid = tid >> 6, lane = tid & 63;
  int n = rfl(blockIdx.x * 4 + wid);
  if (n >= N) return;
  int b = n >> 2;
  int rel = rfl(s1_rel[n]);
  int repl = rfl(s1_ent[n]);
  const float* er = E + (size_t)repl * 64;
  float y = 0.f;
#pragma unroll
  for (int k2 = 0; k2 < 64; ++k2) y = fmaf(er[k2], Wl[k2 * 64 + lane], y);
  y += b1[lane];
  float ss = y * y;
#pragma unroll
  for (int off = 32; off; off >>= 1) ss += __shfl_xor(ss, off);
  float yn = y / fmaxf(sqrtf(ss), EPS_NORM);
  float q = uiE[(size_t)b * 64 + lane] * yn;
  sample_body<false>(q, n, b, lane, items, s1_idx, rel, T2c, kept, p2, wkg2);
}

__global__ __launch_bounds__(256) void k_fin(const int* __restrict__ wkg2,
                                             const float* __restrict__ p2,
                                             const float* __restrict__ lmp1,
                                             float* __restrict__ out2,
                                             float* __restrict__ out3,
                                             int n, int B) {
  int i = blockIdx.x * 256 + threadIdx.x;
  if (i < n) out2[i] = (float)(wkg2[i] & 0x3FFFF);
  if (i < B) {
    float a = ((p2[i * 4] + p2[i * 4 + 1]) + p2[i * 4 + 2]) + p2[i * 4 + 3];
    out3[i] = lmp1[i] + logf(a * 0.25f);
  }
}

// -----------------------------------------------------------------------------
extern "C" void kernel_launch(void* const* d_in, const int* in_sizes, int n_in,
                              void* d_out, int out_size, void* d_ws, size_t ws_size,
                              hipStream_t stream) {
  const int*   users = (const int*)d_in[0];
  const int*   items = (const int*)d_in[1];
  const int*   kg    = (const int*)d_in[2];
  const int*   allc  = (const int*)d_in[3];
  const int*   nrel  = (const int*)d_in[4];
  const float* U     = (const float*)d_in[5];
  const float* E     = (const float*)d_in[6];
  const float* Iemb  = (const float*)d_in[7];
  const float* uiW   = (const float*)d_in[8];
  const float* uib   = (const float*)d_in[9];
  const float* e1W   = (const float*)d_in[10];
  const float* e1b   = (const float*)d_in[11];
  const float* e2W   = (const float*)d_in[12];
  const float* e2b   = (const float*)d_in[13];

  const int B = 4096, NCELL = 3200000, NCAND = 6400, NR4 = 16384, NENT = 200000;

  float* out0    = (float*)d_out;        // cf_kg1 [3.2M]
  float* out_ap1 = out0 + NCELL;         // ap1    [4096]
  float* out2    = out_ap1 + B;          // cf_kg2 [3.2M]
  float* out_ap2 = out2 + NCELL;         // ap2    [4096]

  float* T2c  = (float*)d_ws;            // 409,600 f
  float* uiE  = T2c + 409600;            // 262,144 f
  int*   wkg2 = (int*)(uiE + 262144);    // 3,200,000 i
  int*   s1i  = wkg2 + NCELL;            // 16384
  int*   s1r  = s1i + NR4;               // 16384
  int*   s1e  = s1r + NR4;               // 16384
  int*   kept = s1e + NR4;               // 524,288
  float* p2   = (float*)(kept + 524288); // 16384
  float* lmp1 = p2 + NR4;                // 4096
  float* T1   = lmp1 + B;                // 12,800,000 f (51.2 MB), path A only
  const size_t WS_NEED = ((size_t)(T1 + (size_t)NENT * 64) - (size_t)d_ws);
  const bool pathA = ws_size >= WS_NEED;

  if (pathA) {
    // phase1: T1 (782) + T2c (25) + ui (256) + init (200) = 1263 blocks
    k_phase1<<<1263, 256, 0, stream>>>(E, allc, e1W, e1b, e2W, e2b, U, users,
                                       Iemb, uiW, uib, kg, T1, T2c, uiE,
                                       out0, out2, wkg2);
    // fused score1 + score2 + sample: 4 items per block, cooperative phase A
    k_step4<<<B / 4, 256, 0, stream>>>(items, users, kg, nrel, allc, E, T1, T2c,
                                       uiE, U, out0, out_ap1, s1i, lmp1, p2, wkg2);
    k_fin2<<<(NR4 + 255) / 256, 256, 0, stream>>>(items, s1i, wkg2, p2, lmp1,
                                                  out2, out_ap2, NR4, B);
  } else {
    k_init<<<(NCELL + 255) / 256, 256, 0, stream>>>(kg, out0, wkg2, NCELL);
    k_ui<<<(B + 3) / 4, 256, 0, stream>>>(U, users, Iemb, uiW, uib, uiE, B);
    k_transform64<<<(NCAND + 3) / 4, 256, 0, stream>>>(E, allc, e2W, e2b, T2c, NCAND);
    k_score1<<<B / 4, 256, 0, stream>>>(items, kg, nrel, E, e1W, e1b, uiE,
                                        out0, out_ap1, s1i, s1r, s1e, lmp1, wkg2);
    k_score2<<<(NR4 + 3) / 4, 256, 0, stream>>>(users, s1r, U, E, allc, kept, NR4);
    k_sample<<<(NR4 + 3) / 4, 256, 0, stream>>>(items, s1i, s1r, s1e, E, e1W, e1b,
                                                T2c, uiE, kept, p2, wkg2, NR4);
    k_fin<<<(NCELL + 255) / 256, 256, 0, stream>>>(wkg2, p2, lmp1, out2, out_ap2,
                                                   NCELL, B);
  }
}